// Round 3
// baseline (2104.906 us; speedup 1.0000x reference)
//
#include <hip/hip_runtime.h>

#define HDIM 64
#define NFEAT 32
#define NEMB 32
#define GBATCH 128

// ---------------- degree / norm ----------------

__global__ void init_deg_kernel(float* __restrict__ deg, int N) {
    int i = blockIdx.x * blockDim.x + threadIdx.x;
    if (i < N) deg[i] = 1.0f;   // self-loop weight
}

__global__ void deg_scatter_kernel(const int* __restrict__ ei, const float* __restrict__ ew,
                                   float* __restrict__ deg, int E) {
    int e = blockIdx.x * blockDim.x + threadIdx.x;
    if (e < E) atomicAdd(&deg[ei[E + e]], ew[e]);   // dst row of edge_index
}

__global__ void dinv_kernel(float* __restrict__ deg, int N) {
    int i = blockIdx.x * blockDim.x + threadIdx.x;
    if (i < N) {
        float d = deg[i];
        deg[i] = (d > 0.f) ? rsqrtf(d) : 0.f;   // in-place: deg -> deg^-1/2
    }
}

// ---------------- dense GEMM + fused self-loop/bias init ----------------
// hw[n][k]  = in[n][:] @ W           (needed by scatter's gather)
// hout[n][k] = b[k] + dinv[n]^2 * hw[n][k]   (self-loop term + bias)
// LAYER 0: in = concat(x[n], emb[mapping[n]])   LAYER 1: in = relu(hin[n])

template<int LAYER>
__global__ __launch_bounds__(256) void gemm_kernel(
    const float* __restrict__ x, const int* __restrict__ mapping,
    const float* __restrict__ emb, const float* __restrict__ hin,
    const float* __restrict__ W, const float* __restrict__ bias,
    const float* __restrict__ dinv,
    float* __restrict__ hw, float* __restrict__ hout, int N)
{
    __shared__ float Ws[HDIM * HDIM];   // 16 KB
    __shared__ float ins[4][HDIM];      // 4 node rows staged per iter
    int t = threadIdx.x;
    for (int i = t; i < HDIM * HDIM; i += 256) Ws[i] = W[i];
    __syncthreads();

    int nodeBase = blockIdx.x * 64;     // 64 nodes per block
    int nl = t >> 6;                    // node slot 0..3
    int k  = t & 63;                    // feature / k index
    for (int it = 0; it < 16; ++it) {
        int n = nodeBase + it * 4 + nl;
        float v = 0.f;
        if (n < N) {
            if (LAYER == 0) {
                v = (k < NFEAT) ? x[(size_t)n * NFEAT + k]
                                : emb[(size_t)mapping[n] * NEMB + (k - NFEAT)];
            } else {
                v = fmaxf(hin[(size_t)n * HDIM + k], 0.f);
            }
        }
        ins[nl][k] = v;
        __syncthreads();
        float acc = 0.f;
        #pragma unroll
        for (int kk = 0; kk < HDIM; ++kk)
            acc += ins[nl][kk] * Ws[kk * HDIM + k];
        if (n < N) {
            hw[(size_t)n * HDIM + k] = acc;
            float di = dinv[n];
            hout[(size_t)n * HDIM + k] = bias[k] + di * di * acc;
        }
        __syncthreads();
    }
}

// ---------------- edge scatter: h[dst] += dinv[src]*w*dinv[dst] * hw[src] ----------------
// 2 edges per 64-lane wave; 32 lanes/edge, float2 (2 features) per lane

__global__ __launch_bounds__(256) void scatter_kernel(
    const int* __restrict__ ei, const float* __restrict__ ew,
    const float* __restrict__ dinv, const float* __restrict__ hw,
    float* __restrict__ hout, int E)
{
    int gid = blockIdx.x * blockDim.x + threadIdx.x;
    int e = gid >> 5;
    int lane = gid & 31;
    if (e >= E) return;
    int src = ei[e];
    int dst = ei[E + e];
    float norm = dinv[src] * ew[e] * dinv[dst];
    float2 v = ((const float2*)hw)[(size_t)src * (HDIM / 2) + lane];
    float* o = &hout[(size_t)dst * HDIM + 2 * lane];
    atomicAdd(o,     norm * v.x);
    atomicAdd(o + 1, norm * v.y);
}

// ---------------- pooling ----------------

__global__ void zero_out_kernel(float* __restrict__ out, float* __restrict__ cnt) {
    int i = blockIdx.x * blockDim.x + threadIdx.x;
    if (i < GBATCH * HDIM) out[i] = 0.f;
    if (i < GBATCH) cnt[i] = 0.f;
}

__global__ __launch_bounds__(256) void pool_kernel(
    const float* __restrict__ h, const int* __restrict__ batch,
    float* __restrict__ out, float* __restrict__ cnt, int N)
{
    int gid = blockIdx.x * blockDim.x + threadIdx.x;
    int n = gid >> 5;
    int lane = gid & 31;
    if (n >= N) return;
    int g = batch[n];
    float2 v = ((const float2*)h)[(size_t)n * (HDIM / 2) + lane];
    float* o = &out[g * HDIM + 2 * lane];
    atomicAdd(o,     fmaxf(v.x, 0.f));   // final relu fused here
    atomicAdd(o + 1, fmaxf(v.y, 0.f));
    if (lane == 0) atomicAdd(&cnt[g], 1.0f);
}

__global__ void div_kernel(float* __restrict__ out, const float* __restrict__ cnt) {
    int i = blockIdx.x * blockDim.x + threadIdx.x;
    if (i < GBATCH * HDIM) out[i] /= fmaxf(cnt[i >> 6], 1.0f);
}

// ---------------- launch ----------------

extern "C" void kernel_launch(void* const* d_in, const int* in_sizes, int n_in,
                              void* d_out, int out_size, void* d_ws, size_t ws_size,
                              hipStream_t stream) {
    const float* x       = (const float*)d_in[0];
    const int*   mapping = (const int*)  d_in[1];
    const int*   ei      = (const int*)  d_in[2];
    const float* ew      = (const float*)d_in[3];
    const int*   batch   = (const int*)  d_in[4];
    const float* emb     = (const float*)d_in[5];
    const float* W0      = (const float*)d_in[6];
    const float* b0      = (const float*)d_in[7];
    const float* W1      = (const float*)d_in[8];
    const float* b1      = (const float*)d_in[9];
    float* out = (float*)d_out;

    const int N = in_sizes[1];
    const int E = in_sizes[2] / 2;

    float* ws   = (float*)d_ws;
    float* bufA = ws;                          // [N,64] hw (pre-activation @ W)
    float* bufB = bufA + (size_t)N * HDIM;     // [N,64] aggregated h
    float* deg  = bufB + (size_t)N * HDIM;     // [N]    deg -> dinv (in-place)
    float* cnt  = deg + N;                     // [G]

    // GCN normalization
    init_deg_kernel<<<(N + 255) / 256, 256, 0, stream>>>(deg, N);
    deg_scatter_kernel<<<(E + 255) / 256, 256, 0, stream>>>(ei, ew, deg, E);
    dinv_kernel<<<(N + 255) / 256, 256, 0, stream>>>(deg, N);

    const int gemmGrid = (N + 63) / 64;
    const int scatGrid = (E * 32 + 255) / 256;

    // layer 0 (self-loop + bias init fused into GEMM epilogue)
    gemm_kernel<0><<<gemmGrid, 256, 0, stream>>>(x, mapping, emb, nullptr, W0, b0, deg, bufA, bufB, N);
    scatter_kernel<<<scatGrid, 256, 0, stream>>>(ei, ew, deg, bufA, bufB, E);

    // layer 1 (relu of layer-0 output fused into GEMM load)
    gemm_kernel<1><<<gemmGrid, 256, 0, stream>>>(nullptr, nullptr, nullptr, bufB, W1, b1, deg, bufA, bufB, N);
    scatter_kernel<<<scatGrid, 256, 0, stream>>>(ei, ew, deg, bufA, bufB, E);

    // global mean pool (final relu fused into pool)
    zero_out_kernel<<<(GBATCH * HDIM + 255) / 256, 256, 0, stream>>>(out, cnt);
    pool_kernel<<<(N * 32 + 255) / 256, 256, 0, stream>>>(bufB, batch, out, cnt, N);
    div_kernel<<<(GBATCH * HDIM + 255) / 256, 256, 0, stream>>>(out, cnt);
}

// Round 4
// 805.651 us; speedup vs baseline: 2.6127x; 2.6127x over previous
//
#include <hip/hip_runtime.h>

#define HDIM 64
#define NFEAT 32
#define NEMB 32
#define GBATCH 128
#define SCAN_T 1024

// ---------------- init: deg=1 (self-loop), cnt=0 ----------------

__global__ void init_kernel(float* __restrict__ deg, int* __restrict__ cnt, int N) {
    int i = blockIdx.x * blockDim.x + threadIdx.x;
    if (i < N) { deg[i] = 1.0f; cnt[i] = 0; }
}

// ---------------- histogram: deg[dst] += w, cnt[dst] += 1 ----------------

__global__ void hist_kernel(const int* __restrict__ ei, const float* __restrict__ ew,
                            float* __restrict__ deg, int* __restrict__ cnt, int E) {
    int e = blockIdx.x * blockDim.x + threadIdx.x;
    if (e < E) {
        int dst = ei[E + e];
        atomicAdd(&deg[dst], ew[e]);
        atomicAdd(&cnt[dst], 1);
    }
}

__global__ void dinv_kernel(float* __restrict__ deg, int N) {
    int i = blockIdx.x * blockDim.x + threadIdx.x;
    if (i < N) {
        float d = deg[i];
        deg[i] = (d > 0.f) ? rsqrtf(d) : 0.f;   // in-place: deg -> deg^-1/2
    }
}

// ---------------- single-block exclusive scan: off[i] = sum(cnt[0..i-1]) ----------------

__global__ __launch_bounds__(SCAN_T) void scan_kernel(const int* __restrict__ cnt,
                                                      int* __restrict__ off, int N) {
    __shared__ int lsum[SCAN_T];
    int t = threadIdx.x;
    int chunk = (N + SCAN_T - 1) / SCAN_T;
    int lo = t * chunk, hi = min(lo + chunk, N);
    int s = 0;
    for (int i = lo; i < hi; ++i) s += cnt[i];
    lsum[t] = s;
    __syncthreads();
    for (int d = 1; d < SCAN_T; d <<= 1) {          // Hillis-Steele inclusive scan
        int v = (t >= d) ? lsum[t - d] : 0;
        __syncthreads();
        lsum[t] += v;
        __syncthreads();
    }
    int run = (t > 0) ? lsum[t - 1] : 0;            // exclusive base for this chunk
    for (int i = lo; i < hi; ++i) { off[i] = run; run += cnt[i]; }
}

// ---------------- CSR fill: csr[pos] = (src, norm) bucketed by dst ----------------
// Uses off[] itself as the cursor; afterwards off[n] == end of bucket n.

__global__ void csr_fill_kernel(const int* __restrict__ ei, const float* __restrict__ ew,
                                const float* __restrict__ dinv,
                                int* __restrict__ off, int2* __restrict__ csr, int E) {
    int e = blockIdx.x * blockDim.x + threadIdx.x;
    if (e >= E) return;
    int src = ei[e];
    int dst = ei[E + e];
    int pos = atomicAdd(&off[dst], 1);
    float nm = dinv[src] * ew[e] * dinv[dst];
    csr[pos] = make_int2(src, __float_as_int(nm));
}

// ---------------- dense GEMM: hw[n][k] = in[n][:] @ W ----------------
// LAYER 0: in = concat(x[n], emb[mapping[n]])   LAYER 1: in = relu(hin[n])
// Single LDS stage of 64 input rows; W column held in VGPRs.

template<int LAYER>
__global__ __launch_bounds__(256) void gemm_kernel(
    const float* __restrict__ x, const int* __restrict__ mapping,
    const float* __restrict__ emb, const float* __restrict__ hin,
    const float* __restrict__ W, float* __restrict__ hw, int N)
{
    __shared__ float ins[64][HDIM];   // 16 KB: 64 node rows
    int t = threadIdx.x;
    int nodeBase = blockIdx.x * 64;

    for (int i = t; i < 64 * HDIM; i += 256) {
        int nr = i >> 6, k = i & 63;
        int n = nodeBase + nr;
        float v = 0.f;
        if (n < N) {
            if (LAYER == 0) {
                v = (k < NFEAT) ? x[(size_t)n * NFEAT + k]
                                : emb[(size_t)mapping[n] * NEMB + (k - NFEAT)];
            } else {
                v = fmaxf(hin[(size_t)n * HDIM + k], 0.f);
            }
        }
        ins[nr][k] = v;
    }

    int k = t & 63;
    float wcol[HDIM];
    #pragma unroll
    for (int kk = 0; kk < HDIM; ++kk) wcol[kk] = W[kk * HDIM + k];  // coalesced, L2-hot
    __syncthreads();

    int nl = t >> 6;
    for (int ns = 0; ns < 16; ++ns) {
        int nrow = ns * 4 + nl;
        int n = nodeBase + nrow;
        float acc = 0.f;
        #pragma unroll
        for (int kk = 0; kk < HDIM; ++kk)
            acc += ins[nrow][kk] * wcol[kk];      // LDS broadcast reads
        if (n < N) hw[(size_t)n * HDIM + k] = acc;
    }
}

// ---------------- aggregation: one wave per dst node, zero atomics ----------------
// hout[n] = bias + dinv[n]^2*hw[n] + sum_{e: dst==n} norm_e * hw[src_e]

__global__ __launch_bounds__(256) void agg_kernel(
    const int* __restrict__ off_post, const int2* __restrict__ csr,
    const float* __restrict__ hw, const float* __restrict__ dinv,
    const float* __restrict__ bias, float* __restrict__ hout, int N)
{
    int gid = blockIdx.x * blockDim.x + threadIdx.x;
    int n = gid >> 6, lane = gid & 63;
    if (n >= N) return;
    int s0 = (n > 0) ? off_post[n - 1] : 0;   // off_post[n] == end of bucket n
    int s1 = off_post[n];
    float acc0 = 0.f, acc1 = 0.f;
    int j = s0;
    for (; j + 1 < s1; j += 2) {
        int2 e0 = csr[j], e1 = csr[j + 1];
        acc0 += __int_as_float(e0.y) * hw[(size_t)e0.x * HDIM + lane];
        acc1 += __int_as_float(e1.y) * hw[(size_t)e1.x * HDIM + lane];
    }
    if (j < s1) {
        int2 e0 = csr[j];
        acc0 += __int_as_float(e0.y) * hw[(size_t)e0.x * HDIM + lane];
    }
    float di = dinv[n];
    float r = acc0 + acc1 + di * di * hw[(size_t)n * HDIM + lane] + bias[lane];
    hout[(size_t)n * HDIM + lane] = r;
}

// ---------------- fallback kernels (atomic path, used only if ws too small) ----------------

__global__ void self_init_kernel(const float* __restrict__ hw, const float* __restrict__ dinv,
                                 const float* __restrict__ b, float* __restrict__ hout, int NF) {
    int i = blockIdx.x * blockDim.x + threadIdx.x;
    if (i < NF) {
        int n = i >> 6, f = i & 63;
        float di = dinv[n];
        hout[i] = b[f] + di * di * hw[i];
    }
}

__global__ __launch_bounds__(256) void scatter_kernel(
    const int* __restrict__ ei, const float* __restrict__ ew,
    const float* __restrict__ dinv, const float* __restrict__ hw,
    float* __restrict__ hout, int E)
{
    int gid = blockIdx.x * blockDim.x + threadIdx.x;
    int e = gid >> 5, lane = gid & 31;
    if (e >= E) return;
    int src = ei[e];
    int dst = ei[E + e];
    float norm = dinv[src] * ew[e] * dinv[dst];
    float2 v = ((const float2*)hw)[(size_t)src * (HDIM / 2) + lane];
    float* o = &hout[(size_t)dst * HDIM + 2 * lane];
    atomicAdd(o,     norm * v.x);
    atomicAdd(o + 1, norm * v.y);
}

// ---------------- pooling: one block per graph, batch is sorted -> binary search ----------------

__global__ __launch_bounds__(256) void pool_kernel(
    const float* __restrict__ h, const int* __restrict__ batch,
    float* __restrict__ out, int N)
{
    int g = blockIdx.x;
    int t = threadIdx.x;
    int lane = t & 63, w = t >> 6;
    int lo = 0, hi = N;
    while (lo < hi) { int m = (lo + hi) >> 1; if (batch[m] < g) lo = m + 1; else hi = m; }
    int start = lo;
    hi = N;
    while (lo < hi) { int m = (lo + hi) >> 1; if (batch[m] < g + 1) lo = m + 1; else hi = m; }
    int end = lo;

    float acc = 0.f;
    for (int n = start + w; n < end; n += 4)
        acc += fmaxf(h[(size_t)n * HDIM + lane], 0.f);   // final relu fused

    __shared__ float red[4][HDIM];
    red[w][lane] = acc;
    __syncthreads();
    if (w == 0) {
        float s = red[0][lane] + red[1][lane] + red[2][lane] + red[3][lane];
        float c = (float)(end - start);
        out[g * HDIM + lane] = s / fmaxf(c, 1.f);
    }
}

// ---------------- launch ----------------

extern "C" void kernel_launch(void* const* d_in, const int* in_sizes, int n_in,
                              void* d_out, int out_size, void* d_ws, size_t ws_size,
                              hipStream_t stream) {
    const float* x       = (const float*)d_in[0];
    const int*   mapping = (const int*)  d_in[1];
    const int*   ei      = (const int*)  d_in[2];
    const float* ew      = (const float*)d_in[3];
    const int*   batch   = (const int*)  d_in[4];
    const float* emb     = (const float*)d_in[5];
    const float* W0      = (const float*)d_in[6];
    const float* b0      = (const float*)d_in[7];
    const float* W1      = (const float*)d_in[8];
    const float* b1      = (const float*)d_in[9];
    float* out = (float*)d_out;

    const int N = in_sizes[1];
    const int E = in_sizes[2] / 2;

    // ws layout (8B-aligned first): csr[E] int2 | bufA[N*64] | bufB[N*64] | deg[N] | cnt[N] | off[N+1]
    size_t needed = (size_t)E * 8 + (size_t)N * HDIM * 4 * 2 + (size_t)N * 4 * 2 + ((size_t)N + 1) * 4;

    char* p = (char*)d_ws;
    int2*  csr  = (int2*)p;                 p += (size_t)E * 8;
    float* bufA = (float*)p;                p += (size_t)N * HDIM * 4;
    float* bufB = (float*)p;                p += (size_t)N * HDIM * 4;
    float* deg  = (float*)p;                p += (size_t)N * 4;
    int*   cnt  = (int*)p;                  p += (size_t)N * 4;
    int*   off  = (int*)p;

    const int gemmGrid = (N + 63) / 64;
    const int aggGrid  = (N * 64 + 255) / 256;

    if (ws_size >= needed) {
        // --- CSR build (once per call; shared by both layers) ---
        init_kernel<<<(N + 255) / 256, 256, 0, stream>>>(deg, cnt, N);
        hist_kernel<<<(E + 255) / 256, 256, 0, stream>>>(ei, ew, deg, cnt, E);
        dinv_kernel<<<(N + 255) / 256, 256, 0, stream>>>(deg, N);
        scan_kernel<<<1, SCAN_T, 0, stream>>>(cnt, off, N);
        csr_fill_kernel<<<(E + 255) / 256, 256, 0, stream>>>(ei, ew, deg, off, csr, E);

        // --- layer 0 ---
        gemm_kernel<0><<<gemmGrid, 256, 0, stream>>>(x, mapping, emb, nullptr, W0, bufA, N);
        agg_kernel<<<aggGrid, 256, 0, stream>>>(off, csr, bufA, deg, b0, bufB, N);

        // --- layer 1 ---
        gemm_kernel<1><<<gemmGrid, 256, 0, stream>>>(nullptr, nullptr, nullptr, bufB, W1, bufA, N);
        agg_kernel<<<aggGrid, 256, 0, stream>>>(off, csr, bufA, deg, b1, bufB, N);
    } else {
        // --- fallback: proven atomic path (round 3) ---
        const int NF = N * HDIM;
        const int scatGrid = (E * 32 + 255) / 256;
        float* fdeg = bufB + (size_t)N * HDIM;  // matches round-3 layout budget
        init_kernel<<<(N + 255) / 256, 256, 0, stream>>>(fdeg, cnt, N);
        hist_kernel<<<(E + 255) / 256, 256, 0, stream>>>(ei, ew, fdeg, cnt, E);
        dinv_kernel<<<(N + 255) / 256, 256, 0, stream>>>(fdeg, N);

        gemm_kernel<0><<<gemmGrid, 256, 0, stream>>>(x, mapping, emb, nullptr, W0, bufA, N);
        self_init_kernel<<<(NF + 255) / 256, 256, 0, stream>>>(bufA, fdeg, b0, bufB, NF);
        scatter_kernel<<<scatGrid, 256, 0, stream>>>(ei, ew, fdeg, bufA, bufB, E);

        gemm_kernel<1><<<gemmGrid, 256, 0, stream>>>(nullptr, nullptr, nullptr, bufB, W1, bufA, N);
        self_init_kernel<<<(NF + 255) / 256, 256, 0, stream>>>(bufA, fdeg, b1, bufB, NF);
        scatter_kernel<<<scatGrid, 256, 0, stream>>>(ei, ew, fdeg, bufA, bufB, E);
    }

    // --- global mean pool (deterministic, no atomics) ---
    pool_kernel<<<GBATCH, 256, 0, stream>>>(bufB, batch, out, N);
}

// Round 5
// 641.010 us; speedup vs baseline: 3.2837x; 1.2568x over previous
//
#include <hip/hip_runtime.h>

#define HDIM 64
#define NFEAT 32
#define NEMB 32
#define GBATCH 128
#define SB 256

// ---------------- init: deg=1 (self-loop), cnt=0 ----------------

__global__ void init_kernel(float* __restrict__ deg, int* __restrict__ cnt, int N) {
    int i = blockIdx.x * blockDim.x + threadIdx.x;
    if (i < N) { deg[i] = 1.0f; cnt[i] = 0; }
}

// ---------------- histogram: deg[dst] += w, cnt[dst] += 1 ----------------

__global__ void hist_kernel(const int* __restrict__ ei, const float* __restrict__ ew,
                            float* __restrict__ deg, int* __restrict__ cnt, int E) {
    int e = blockIdx.x * blockDim.x + threadIdx.x;
    if (e < E) {
        int dst = ei[E + e];
        atomicAdd(&deg[dst], ew[e]);
        atomicAdd(&cnt[dst], 1);
    }
}

__global__ void dinv_kernel(float* __restrict__ deg, int N) {
    int i = blockIdx.x * blockDim.x + threadIdx.x;
    if (i < N) {
        float d = deg[i];
        deg[i] = (d > 0.f) ? rsqrtf(d) : 0.f;   // in-place: deg -> deg^-1/2
    }
}

// ---------------- 3-phase device-wide exclusive scan of cnt -> off ----------------
// phase 1: per-block reduce           phase 2: scan block sums (1 block)
// phase 3: per-block local scan + base

__global__ __launch_bounds__(SB) void scan1_kernel(const int* __restrict__ cnt,
                                                   int* __restrict__ bsum, int N) {
    __shared__ int red[SB];
    int t = threadIdx.x;
    int i = blockIdx.x * SB + t;
    red[t] = (i < N) ? cnt[i] : 0;
    __syncthreads();
    for (int d = SB >> 1; d > 0; d >>= 1) {
        if (t < d) red[t] += red[t + d];
        __syncthreads();
    }
    if (t == 0) bsum[blockIdx.x] = red[0];
}

__global__ __launch_bounds__(512) void scan2_kernel(int* __restrict__ bsum, int nb) {
    __shared__ int s[512];
    int t = threadIdx.x;
    int v = (t < nb) ? bsum[t] : 0;
    s[t] = v;
    __syncthreads();
    for (int d = 1; d < 512; d <<= 1) {
        int u = (t >= d) ? s[t - d] : 0;
        __syncthreads();
        s[t] += u;
        __syncthreads();
    }
    if (t < nb) bsum[t] = s[t] - v;   // exclusive
}

__global__ __launch_bounds__(SB) void scan3_kernel(const int* __restrict__ cnt,
                                                   const int* __restrict__ bsum,
                                                   int* __restrict__ off, int N) {
    __shared__ int s[SB];
    int t = threadIdx.x;
    int i = blockIdx.x * SB + t;
    int v = (i < N) ? cnt[i] : 0;
    s[t] = v;
    __syncthreads();
    for (int d = 1; d < SB; d <<= 1) {
        int u = (t >= d) ? s[t - d] : 0;
        __syncthreads();
        s[t] += u;
        __syncthreads();
    }
    if (i < N) off[i] = bsum[blockIdx.x] + s[t] - v;   // exclusive
}

// ---------------- CSR fill: csr[pos] = (src, norm) bucketed by dst ----------------
// Uses off[] itself as the cursor; afterwards off[n] == end of bucket n.

__global__ void csr_fill_kernel(const int* __restrict__ ei, const float* __restrict__ ew,
                                const float* __restrict__ dinv,
                                int* __restrict__ off, int2* __restrict__ csr, int E) {
    int e = blockIdx.x * blockDim.x + threadIdx.x;
    if (e >= E) return;
    int src = ei[e];
    int dst = ei[E + e];
    int pos = atomicAdd(&off[dst], 1);
    float nm = dinv[src] * ew[e] * dinv[dst];
    csr[pos] = make_int2(src, __float_as_int(nm));
}

// ---------------- dense GEMM: hw[n][k] = in[n][:] @ W ----------------
// LAYER 0: in = concat(x[n], emb[mapping[n]])   LAYER 1: in = relu(hin[n])

template<int LAYER>
__global__ __launch_bounds__(256) void gemm_kernel(
    const float* __restrict__ x, const int* __restrict__ mapping,
    const float* __restrict__ emb, const float* __restrict__ hin,
    const float* __restrict__ W, float* __restrict__ hw, int N)
{
    __shared__ float ins[64][HDIM];   // 16 KB: 64 node rows
    int t = threadIdx.x;
    int nodeBase = blockIdx.x * 64;

    for (int i = t; i < 64 * HDIM; i += 256) {
        int nr = i >> 6, k = i & 63;
        int n = nodeBase + nr;
        float v = 0.f;
        if (n < N) {
            if (LAYER == 0) {
                v = (k < NFEAT) ? x[(size_t)n * NFEAT + k]
                                : emb[(size_t)mapping[n] * NEMB + (k - NFEAT)];
            } else {
                v = fmaxf(hin[(size_t)n * HDIM + k], 0.f);
            }
        }
        ins[nr][k] = v;
    }

    int k = t & 63;
    float wcol[HDIM];
    #pragma unroll
    for (int kk = 0; kk < HDIM; ++kk) wcol[kk] = W[kk * HDIM + k];  // coalesced, L2-hot
    __syncthreads();

    int nl = t >> 6;
    for (int ns = 0; ns < 16; ++ns) {
        int nrow = ns * 4 + nl;
        int n = nodeBase + nrow;
        float acc = 0.f;
        #pragma unroll
        for (int kk = 0; kk < HDIM; ++kk)
            acc += ins[nrow][kk] * wcol[kk];      // LDS broadcast reads
        if (n < N) hw[(size_t)n * HDIM + k] = acc;
    }
}

// ---------------- aggregation: one wave per dst node, zero atomics ----------------
// hout[n] = bias + dinv[n]^2*hw[n] + sum_{e: dst==n} norm_e * hw[src_e]

__global__ __launch_bounds__(256) void agg_kernel(
    const int* __restrict__ off_post, const int2* __restrict__ csr,
    const float* __restrict__ hw, const float* __restrict__ dinv,
    const float* __restrict__ bias, float* __restrict__ hout, int N)
{
    int gid = blockIdx.x * blockDim.x + threadIdx.x;
    int n = gid >> 6, lane = gid & 63;
    if (n >= N) return;
    int s0 = (n > 0) ? off_post[n - 1] : 0;   // off_post[n] == end of bucket n
    int s1 = off_post[n];
    float acc0 = 0.f, acc1 = 0.f;
    int j = s0;
    for (; j + 1 < s1; j += 2) {
        int2 e0 = csr[j], e1 = csr[j + 1];
        acc0 += __int_as_float(e0.y) * hw[(size_t)e0.x * HDIM + lane];
        acc1 += __int_as_float(e1.y) * hw[(size_t)e1.x * HDIM + lane];
    }
    if (j < s1) {
        int2 e0 = csr[j];
        acc0 += __int_as_float(e0.y) * hw[(size_t)e0.x * HDIM + lane];
    }
    float di = dinv[n];
    float r = acc0 + acc1 + di * di * hw[(size_t)n * HDIM + lane] + bias[lane];
    hout[(size_t)n * HDIM + lane] = r;
}

// ---------------- fallback kernels (atomic path, used only if ws too small) ----------------

__global__ void self_init_kernel(const float* __restrict__ hw, const float* __restrict__ dinv,
                                 const float* __restrict__ b, float* __restrict__ hout, int NF) {
    int i = blockIdx.x * blockDim.x + threadIdx.x;
    if (i < NF) {
        int n = i >> 6, f = i & 63;
        float di = dinv[n];
        hout[i] = b[f] + di * di * hw[i];
    }
}

__global__ __launch_bounds__(256) void scatter_kernel(
    const int* __restrict__ ei, const float* __restrict__ ew,
    const float* __restrict__ dinv, const float* __restrict__ hw,
    float* __restrict__ hout, int E)
{
    int gid = blockIdx.x * blockDim.x + threadIdx.x;
    int e = gid >> 5, lane = gid & 31;
    if (e >= E) return;
    int src = ei[e];
    int dst = ei[E + e];
    float norm = dinv[src] * ew[e] * dinv[dst];
    float2 v = ((const float2*)hw)[(size_t)src * (HDIM / 2) + lane];
    float* o = &hout[(size_t)dst * HDIM + 2 * lane];
    atomicAdd(o,     norm * v.x);
    atomicAdd(o + 1, norm * v.y);
}

// ---------------- pooling: one block per graph, batch is sorted -> binary search ----------------

__global__ __launch_bounds__(256) void pool_kernel(
    const float* __restrict__ h, const int* __restrict__ batch,
    float* __restrict__ out, int N)
{
    int g = blockIdx.x;
    int t = threadIdx.x;
    int lane = t & 63, w = t >> 6;
    int lo = 0, hi = N;
    while (lo < hi) { int m = (lo + hi) >> 1; if (batch[m] < g) lo = m + 1; else hi = m; }
    int start = lo;
    hi = N;
    while (lo < hi) { int m = (lo + hi) >> 1; if (batch[m] < g + 1) lo = m + 1; else hi = m; }
    int end = lo;

    float acc = 0.f;
    for (int n = start + w; n < end; n += 4)
        acc += fmaxf(h[(size_t)n * HDIM + lane], 0.f);   // final relu fused

    __shared__ float red[4][HDIM];
    red[w][lane] = acc;
    __syncthreads();
    if (w == 0) {
        float s = red[0][lane] + red[1][lane] + red[2][lane] + red[3][lane];
        float c = (float)(end - start);
        out[g * HDIM + lane] = s / fmaxf(c, 1.f);
    }
}

// ---------------- launch ----------------

extern "C" void kernel_launch(void* const* d_in, const int* in_sizes, int n_in,
                              void* d_out, int out_size, void* d_ws, size_t ws_size,
                              hipStream_t stream) {
    const float* x       = (const float*)d_in[0];
    const int*   mapping = (const int*)  d_in[1];
    const int*   ei      = (const int*)  d_in[2];
    const float* ew      = (const float*)d_in[3];
    const int*   batch   = (const int*)  d_in[4];
    const float* emb     = (const float*)d_in[5];
    const float* W0      = (const float*)d_in[6];
    const float* b0      = (const float*)d_in[7];
    const float* W1      = (const float*)d_in[8];
    const float* b1      = (const float*)d_in[9];
    float* out = (float*)d_out;

    const int N = in_sizes[1];
    const int E = in_sizes[2] / 2;
    const int nScanB = (N + SB - 1) / SB;   // 391 for N=100000 (fits scan2's 512)

    // ws layout (8B-aligned first):
    // csr[E] int2 | bufA[N*64] | bufB[N*64] | deg[N] | cnt[N] | off[N+1] | bsum[nScanB]
    size_t needed = (size_t)E * 8 + (size_t)N * HDIM * 4 * 2 + (size_t)N * 4 * 2
                  + ((size_t)N + 1) * 4 + (size_t)nScanB * 4;

    char* p = (char*)d_ws;
    int2*  csr  = (int2*)p;                 p += (size_t)E * 8;
    float* bufA = (float*)p;                p += (size_t)N * HDIM * 4;
    float* bufB = (float*)p;                p += (size_t)N * HDIM * 4;
    float* deg  = (float*)p;                p += (size_t)N * 4;
    int*   cnt  = (int*)p;                  p += (size_t)N * 4;
    int*   off  = (int*)p;                  p += ((size_t)N + 1) * 4;
    int*   bsum = (int*)p;

    const int gemmGrid = (N + 63) / 64;
    const int aggGrid  = (N * 64 + 255) / 256;

    if (ws_size >= needed && nScanB <= 512) {
        // --- CSR build (once per call; shared by both layers) ---
        init_kernel<<<(N + 255) / 256, 256, 0, stream>>>(deg, cnt, N);
        hist_kernel<<<(E + 255) / 256, 256, 0, stream>>>(ei, ew, deg, cnt, E);
        dinv_kernel<<<(N + 255) / 256, 256, 0, stream>>>(deg, N);
        scan1_kernel<<<nScanB, SB, 0, stream>>>(cnt, bsum, N);
        scan2_kernel<<<1, 512, 0, stream>>>(bsum, nScanB);
        scan3_kernel<<<nScanB, SB, 0, stream>>>(cnt, bsum, off, N);
        csr_fill_kernel<<<(E + 255) / 256, 256, 0, stream>>>(ei, ew, deg, off, csr, E);

        // --- layer 0 ---
        gemm_kernel<0><<<gemmGrid, 256, 0, stream>>>(x, mapping, emb, nullptr, W0, bufA, N);
        agg_kernel<<<aggGrid, 256, 0, stream>>>(off, csr, bufA, deg, b0, bufB, N);

        // --- layer 1 ---
        gemm_kernel<1><<<gemmGrid, 256, 0, stream>>>(nullptr, nullptr, nullptr, bufB, W1, bufA, N);
        agg_kernel<<<aggGrid, 256, 0, stream>>>(off, csr, bufA, deg, b1, bufB, N);
    } else {
        // --- fallback: proven atomic path (round 3) ---
        const int NF = N * HDIM;
        const int scatGrid = (E * 32 + 255) / 256;
        float* fdeg = bufB + (size_t)N * HDIM;
        init_kernel<<<(N + 255) / 256, 256, 0, stream>>>(fdeg, cnt, N);
        hist_kernel<<<(E + 255) / 256, 256, 0, stream>>>(ei, ew, fdeg, cnt, E);
        dinv_kernel<<<(N + 255) / 256, 256, 0, stream>>>(fdeg, N);

        gemm_kernel<0><<<gemmGrid, 256, 0, stream>>>(x, mapping, emb, nullptr, W0, bufA, N);
        self_init_kernel<<<(NF + 255) / 256, 256, 0, stream>>>(bufA, fdeg, b0, bufB, NF);
        scatter_kernel<<<scatGrid, 256, 0, stream>>>(ei, ew, fdeg, bufA, bufB, E);

        gemm_kernel<1><<<gemmGrid, 256, 0, stream>>>(nullptr, nullptr, nullptr, bufB, W1, bufA, N);
        self_init_kernel<<<(NF + 255) / 256, 256, 0, stream>>>(bufA, fdeg, b1, bufB, NF);
        scatter_kernel<<<scatGrid, 256, 0, stream>>>(ei, ew, fdeg, bufA, bufB, E);
    }

    // --- global mean pool (deterministic, no atomics) ---
    pool_kernel<<<GBATCH, 256, 0, stream>>>(bufB, batch, out, N);
}

// Round 6
// 549.615 us; speedup vs baseline: 3.8298x; 1.1663x over previous
//
#include <hip/hip_runtime.h>

#define HDIM 64
#define NFEAT 32
#define NEMB 32
#define GBATCH 128
#define MAXD 48
#define SPILL_CAP 4096
#define SB 256

// ================= fast path: one-pass ELL build =================

__global__ void init_ell_kernel(int* __restrict__ cnt, int* __restrict__ spillCnt, int N) {
    int i = blockIdx.x * blockDim.x + threadIdx.x;
    if (i < N) cnt[i] = 0;
    if (i == 0) *spillCnt = 0;
}

// one atomic per edge; ELL row-major [N][MAXD] of (src, ew)
__global__ void ell_fill_kernel(const int* __restrict__ ei, const float* __restrict__ ew,
                                int* __restrict__ cnt, int2* __restrict__ ell,
                                int4* __restrict__ spill, int* __restrict__ spillCnt, int E) {
    int e = blockIdx.x * blockDim.x + threadIdx.x;
    if (e >= E) return;
    int src = ei[e];
    int dst = ei[E + e];
    float w = ew[e];
    int slot = atomicAdd(&cnt[dst], 1);
    if (slot < MAXD) {
        ell[(size_t)dst * MAXD + slot] = make_int2(src, __float_as_int(w));
    } else {
        int sp = atomicAdd(spillCnt, 1);
        if (sp < SPILL_CAP) spill[sp] = make_int4(src, dst, __float_as_int(w), 0);
    }
}

// deg[n] = 1 (self-loop) + sum of ew over ELL row; wave per node, shuffle reduce
__global__ __launch_bounds__(256) void degsum_kernel(const int2* __restrict__ ell,
                                                     const int* __restrict__ cnt,
                                                     float* __restrict__ deg, int N) {
    int gid = blockIdx.x * blockDim.x + threadIdx.x;
    int n = gid >> 6, lane = gid & 63;
    if (n >= N) return;
    int c = min(cnt[n], MAXD);
    float s = (lane < c) ? __int_as_float(ell[(size_t)n * MAXD + lane].y) : 0.f;
    #pragma unroll
    for (int d = 32; d > 0; d >>= 1) s += __shfl_down(s, d, 64);
    if (lane == 0) deg[n] = 1.f + s;
}

__global__ void spill_deg_kernel(const int4* __restrict__ spill, const int* __restrict__ spillCnt,
                                 float* __restrict__ deg) {
    int e = blockIdx.x * blockDim.x + threadIdx.x;
    int ns = min(*spillCnt, SPILL_CAP);
    if (e < ns) atomicAdd(&deg[spill[e].y], __int_as_float(spill[e].z));
}

__global__ void dinv_kernel(float* __restrict__ deg, int N) {
    int i = blockIdx.x * blockDim.x + threadIdx.x;
    if (i < N) {
        float d = deg[i];
        deg[i] = (d > 0.f) ? rsqrtf(d) : 0.f;   // in-place: deg -> deg^-1/2
    }
}

// hout[n] = bias + dinv[n]^2*hw[n] + dinv[n] * sum_j dinv[src_j]*ew_j * hw[src_j]
__global__ __launch_bounds__(256) void agg_kernel(
    const int2* __restrict__ ell, const int* __restrict__ cnt,
    const float* __restrict__ hw, const float* __restrict__ dinv,
    const float* __restrict__ bias, float* __restrict__ hout, int N)
{
    int gid = blockIdx.x * blockDim.x + threadIdx.x;
    int n = gid >> 6, lane = gid & 63;
    if (n >= N) return;
    int c = min(cnt[n], MAXD);
    const int2* row = ell + (size_t)n * MAXD;
    float acc0 = 0.f, acc1 = 0.f;
    int j = 0;
    for (; j + 1 < c; j += 2) {
        int2 e0 = row[j], e1 = row[j + 1];
        float n0 = dinv[e0.x] * __int_as_float(e0.y);
        float n1 = dinv[e1.x] * __int_as_float(e1.y);
        acc0 += n0 * hw[(size_t)e0.x * HDIM + lane];
        acc1 += n1 * hw[(size_t)e1.x * HDIM + lane];
    }
    if (j < c) {
        int2 e0 = row[j];
        acc0 += dinv[e0.x] * __int_as_float(e0.y) * hw[(size_t)e0.x * HDIM + lane];
    }
    float dn = dinv[n];
    hout[(size_t)n * HDIM + lane] =
        dn * (acc0 + acc1) + dn * dn * hw[(size_t)n * HDIM + lane] + bias[lane];
}

// rare overflow edges: atomic add after agg's plain write
__global__ __launch_bounds__(256) void spill_agg_kernel(
    const int4* __restrict__ spill, const int* __restrict__ spillCnt,
    const float* __restrict__ hw, const float* __restrict__ dinv, float* __restrict__ hout)
{
    int gid = blockIdx.x * blockDim.x + threadIdx.x;
    int e = gid >> 6, lane = gid & 63;
    int ns = min(*spillCnt, SPILL_CAP);
    if (e >= ns) return;
    int4 sp = spill[e];
    float nm = dinv[sp.x] * __int_as_float(sp.z) * dinv[sp.y];
    atomicAdd(&hout[(size_t)sp.y * HDIM + lane], nm * hw[(size_t)sp.x * HDIM + lane]);
}

// ================= shared: GEMM =================

template<int LAYER>
__global__ __launch_bounds__(256) void gemm_kernel(
    const float* __restrict__ x, const int* __restrict__ mapping,
    const float* __restrict__ emb, const float* __restrict__ hin,
    const float* __restrict__ W, float* __restrict__ hw, int N)
{
    __shared__ float ins[64][HDIM];   // 16 KB: 64 node rows
    int t = threadIdx.x;
    int nodeBase = blockIdx.x * 64;

    for (int i = t; i < 64 * HDIM; i += 256) {
        int nr = i >> 6, k = i & 63;
        int n = nodeBase + nr;
        float v = 0.f;
        if (n < N) {
            if (LAYER == 0) {
                v = (k < NFEAT) ? x[(size_t)n * NFEAT + k]
                                : emb[(size_t)mapping[n] * NEMB + (k - NFEAT)];
            } else {
                v = fmaxf(hin[(size_t)n * HDIM + k], 0.f);
            }
        }
        ins[nr][k] = v;
    }

    int k = t & 63;
    float wcol[HDIM];
    #pragma unroll
    for (int kk = 0; kk < HDIM; ++kk) wcol[kk] = W[kk * HDIM + k];
    __syncthreads();

    int nl = t >> 6;
    for (int ns = 0; ns < 16; ++ns) {
        int nrow = ns * 4 + nl;
        int n = nodeBase + nrow;
        float acc = 0.f;
        #pragma unroll
        for (int kk = 0; kk < HDIM; ++kk)
            acc += ins[nrow][kk] * wcol[kk];
        if (n < N) hw[(size_t)n * HDIM + k] = acc;
    }
}

// ================= fallback tier 2: CSR path (round-5, proven 641 us) =================

__global__ void init_kernel(float* __restrict__ deg, int* __restrict__ cnt, int N) {
    int i = blockIdx.x * blockDim.x + threadIdx.x;
    if (i < N) { deg[i] = 1.0f; cnt[i] = 0; }
}

__global__ void hist_kernel(const int* __restrict__ ei, const float* __restrict__ ew,
                            float* __restrict__ deg, int* __restrict__ cnt, int E) {
    int e = blockIdx.x * blockDim.x + threadIdx.x;
    if (e < E) {
        int dst = ei[E + e];
        atomicAdd(&deg[dst], ew[e]);
        atomicAdd(&cnt[dst], 1);
    }
}

__global__ __launch_bounds__(SB) void scan1_kernel(const int* __restrict__ cnt,
                                                   int* __restrict__ bsum, int N) {
    __shared__ int red[SB];
    int t = threadIdx.x;
    int i = blockIdx.x * SB + t;
    red[t] = (i < N) ? cnt[i] : 0;
    __syncthreads();
    for (int d = SB >> 1; d > 0; d >>= 1) {
        if (t < d) red[t] += red[t + d];
        __syncthreads();
    }
    if (t == 0) bsum[blockIdx.x] = red[0];
}

__global__ __launch_bounds__(512) void scan2_kernel(int* __restrict__ bsum, int nb) {
    __shared__ int s[512];
    int t = threadIdx.x;
    int v = (t < nb) ? bsum[t] : 0;
    s[t] = v;
    __syncthreads();
    for (int d = 1; d < 512; d <<= 1) {
        int u = (t >= d) ? s[t - d] : 0;
        __syncthreads();
        s[t] += u;
        __syncthreads();
    }
    if (t < nb) bsum[t] = s[t] - v;
}

__global__ __launch_bounds__(SB) void scan3_kernel(const int* __restrict__ cnt,
                                                   const int* __restrict__ bsum,
                                                   int* __restrict__ off, int N) {
    __shared__ int s[SB];
    int t = threadIdx.x;
    int i = blockIdx.x * SB + t;
    int v = (i < N) ? cnt[i] : 0;
    s[t] = v;
    __syncthreads();
    for (int d = 1; d < SB; d <<= 1) {
        int u = (t >= d) ? s[t - d] : 0;
        __syncthreads();
        s[t] += u;
        __syncthreads();
    }
    if (i < N) off[i] = bsum[blockIdx.x] + s[t] - v;
}

__global__ void csr_fill_kernel(const int* __restrict__ ei, const float* __restrict__ ew,
                                const float* __restrict__ dinv,
                                int* __restrict__ off, int2* __restrict__ csr, int E) {
    int e = blockIdx.x * blockDim.x + threadIdx.x;
    if (e >= E) return;
    int src = ei[e];
    int dst = ei[E + e];
    int pos = atomicAdd(&off[dst], 1);
    float nm = dinv[src] * ew[e] * dinv[dst];
    csr[pos] = make_int2(src, __float_as_int(nm));
}

__global__ __launch_bounds__(256) void agg_csr_kernel(
    const int* __restrict__ off_post, const int2* __restrict__ csr,
    const float* __restrict__ hw, const float* __restrict__ dinv,
    const float* __restrict__ bias, float* __restrict__ hout, int N)
{
    int gid = blockIdx.x * blockDim.x + threadIdx.x;
    int n = gid >> 6, lane = gid & 63;
    if (n >= N) return;
    int s0 = (n > 0) ? off_post[n - 1] : 0;
    int s1 = off_post[n];
    float acc0 = 0.f, acc1 = 0.f;
    int j = s0;
    for (; j + 1 < s1; j += 2) {
        int2 e0 = csr[j], e1 = csr[j + 1];
        acc0 += __int_as_float(e0.y) * hw[(size_t)e0.x * HDIM + lane];
        acc1 += __int_as_float(e1.y) * hw[(size_t)e1.x * HDIM + lane];
    }
    if (j < s1) {
        int2 e0 = csr[j];
        acc0 += __int_as_float(e0.y) * hw[(size_t)e0.x * HDIM + lane];
    }
    float di = dinv[n];
    hout[(size_t)n * HDIM + lane] =
        acc0 + acc1 + di * di * hw[(size_t)n * HDIM + lane] + bias[lane];
}

// ================= fallback tier 3: atomic scatter =================

__global__ void self_init_kernel(const float* __restrict__ hw, const float* __restrict__ dinv,
                                 const float* __restrict__ b, float* __restrict__ hout, int NF) {
    int i = blockIdx.x * blockDim.x + threadIdx.x;
    if (i < NF) {
        int n = i >> 6, f = i & 63;
        float di = dinv[n];
        hout[i] = b[f] + di * di * hw[i];
    }
}

__global__ __launch_bounds__(256) void scatter_kernel(
    const int* __restrict__ ei, const float* __restrict__ ew,
    const float* __restrict__ dinv, const float* __restrict__ hw,
    float* __restrict__ hout, int E)
{
    int gid = blockIdx.x * blockDim.x + threadIdx.x;
    int e = gid >> 5, lane = gid & 31;
    if (e >= E) return;
    int src = ei[e];
    int dst = ei[E + e];
    float norm = dinv[src] * ew[e] * dinv[dst];
    float2 v = ((const float2*)hw)[(size_t)src * (HDIM / 2) + lane];
    float* o = &hout[(size_t)dst * HDIM + 2 * lane];
    atomicAdd(o,     norm * v.x);
    atomicAdd(o + 1, norm * v.y);
}

// ================= pooling =================

__global__ __launch_bounds__(256) void pool_kernel(
    const float* __restrict__ h, const int* __restrict__ batch,
    float* __restrict__ out, int N)
{
    int g = blockIdx.x;
    int t = threadIdx.x;
    int lane = t & 63, w = t >> 6;
    int lo = 0, hi = N;
    while (lo < hi) { int m = (lo + hi) >> 1; if (batch[m] < g) lo = m + 1; else hi = m; }
    int start = lo;
    hi = N;
    while (lo < hi) { int m = (lo + hi) >> 1; if (batch[m] < g + 1) lo = m + 1; else hi = m; }
    int end = lo;

    float acc = 0.f;
    for (int n = start + w; n < end; n += 4)
        acc += fmaxf(h[(size_t)n * HDIM + lane], 0.f);

    __shared__ float red[4][HDIM];
    red[w][lane] = acc;
    __syncthreads();
    if (w == 0) {
        float s = red[0][lane] + red[1][lane] + red[2][lane] + red[3][lane];
        float c = (float)(end - start);
        out[g * HDIM + lane] = s / fmaxf(c, 1.f);
    }
}

// ================= launch =================

extern "C" void kernel_launch(void* const* d_in, const int* in_sizes, int n_in,
                              void* d_out, int out_size, void* d_ws, size_t ws_size,
                              hipStream_t stream) {
    const float* x       = (const float*)d_in[0];
    const int*   mapping = (const int*)  d_in[1];
    const int*   ei      = (const int*)  d_in[2];
    const float* ew      = (const float*)d_in[3];
    const int*   batch   = (const int*)  d_in[4];
    const float* emb     = (const float*)d_in[5];
    const float* W0      = (const float*)d_in[6];
    const float* b0      = (const float*)d_in[7];
    const float* W1      = (const float*)d_in[8];
    const float* b1      = (const float*)d_in[9];
    float* out = (float*)d_out;

    const int N = in_sizes[1];
    const int E = in_sizes[2] / 2;
    const int nScanB = (N + SB - 1) / SB;

    const int gemmGrid = (N + 63) / 64;
    const int nodeGrid = (N * 64 + 255) / 256;   // wave per node

    // --- ELL layout: ell[N*MAXD] int2 | bufA | bufB | deg[N] | cnt[N] | spill | spillCnt ---
    size_t need_ell = (size_t)N * MAXD * 8 + (size_t)N * HDIM * 4 * 2 + (size_t)N * 4 * 2
                    + (size_t)SPILL_CAP * 16 + 16;
    // --- CSR layout: csr[E] int2 | bufA | bufB | deg[N] | cnt[N] | off[N+1] | bsum ---
    size_t need_csr = (size_t)E * 8 + (size_t)N * HDIM * 4 * 2 + (size_t)N * 4 * 2
                    + ((size_t)N + 1) * 4 + (size_t)nScanB * 4;

    if (ws_size >= need_ell) {
        char* p = (char*)d_ws;
        int2*  ell  = (int2*)p;                p += (size_t)N * MAXD * 8;
        float* bufA = (float*)p;               p += (size_t)N * HDIM * 4;
        float* bufB = (float*)p;               p += (size_t)N * HDIM * 4;
        float* deg  = (float*)p;               p += (size_t)N * 4;
        int*   cnt  = (int*)p;                 p += (size_t)N * 4;
        int4*  spill = (int4*)p;               p += (size_t)SPILL_CAP * 16;
        int*   spillCnt = (int*)p;

        const int spillGrid = (SPILL_CAP * 64 + 255) / 256;

        init_ell_kernel<<<(N + 255) / 256, 256, 0, stream>>>(cnt, spillCnt, N);
        ell_fill_kernel<<<(E + 255) / 256, 256, 0, stream>>>(ei, ew, cnt, ell, spill, spillCnt, E);
        degsum_kernel<<<nodeGrid, 256, 0, stream>>>(ell, cnt, deg, N);
        spill_deg_kernel<<<(SPILL_CAP + 255) / 256, 256, 0, stream>>>(spill, spillCnt, deg);
        dinv_kernel<<<(N + 255) / 256, 256, 0, stream>>>(deg, N);

        gemm_kernel<0><<<gemmGrid, 256, 0, stream>>>(x, mapping, emb, nullptr, W0, bufA, N);
        agg_kernel<<<nodeGrid, 256, 0, stream>>>(ell, cnt, bufA, deg, b0, bufB, N);
        spill_agg_kernel<<<spillGrid, 256, 0, stream>>>(spill, spillCnt, bufA, deg, bufB);

        gemm_kernel<1><<<gemmGrid, 256, 0, stream>>>(nullptr, nullptr, nullptr, bufB, W1, bufA, N);
        agg_kernel<<<nodeGrid, 256, 0, stream>>>(ell, cnt, bufA, deg, b1, bufB, N);
        spill_agg_kernel<<<spillGrid, 256, 0, stream>>>(spill, spillCnt, bufA, deg, bufB);

        pool_kernel<<<GBATCH, 256, 0, stream>>>(bufB, batch, out, N);
    } else if (ws_size >= need_csr && nScanB <= 512) {
        char* p = (char*)d_ws;
        int2*  csr  = (int2*)p;                p += (size_t)E * 8;
        float* bufA = (float*)p;               p += (size_t)N * HDIM * 4;
        float* bufB = (float*)p;               p += (size_t)N * HDIM * 4;
        float* deg  = (float*)p;               p += (size_t)N * 4;
        int*   cnt  = (int*)p;                 p += (size_t)N * 4;
        int*   off  = (int*)p;                 p += ((size_t)N + 1) * 4;
        int*   bsum = (int*)p;

        init_kernel<<<(N + 255) / 256, 256, 0, stream>>>(deg, cnt, N);
        hist_kernel<<<(E + 255) / 256, 256, 0, stream>>>(ei, ew, deg, cnt, E);
        dinv_kernel<<<(N + 255) / 256, 256, 0, stream>>>(deg, N);
        scan1_kernel<<<nScanB, SB, 0, stream>>>(cnt, bsum, N);
        scan2_kernel<<<1, 512, 0, stream>>>(bsum, nScanB);
        scan3_kernel<<<nScanB, SB, 0, stream>>>(cnt, bsum, off, N);
        csr_fill_kernel<<<(E + 255) / 256, 256, 0, stream>>>(ei, ew, deg, off, csr, E);

        gemm_kernel<0><<<gemmGrid, 256, 0, stream>>>(x, mapping, emb, nullptr, W0, bufA, N);
        agg_csr_kernel<<<nodeGrid, 256, 0, stream>>>(off, csr, bufA, deg, b0, bufB, N);
        gemm_kernel<1><<<gemmGrid, 256, 0, stream>>>(nullptr, nullptr, nullptr, bufB, W1, bufA, N);
        agg_csr_kernel<<<nodeGrid, 256, 0, stream>>>(off, csr, bufA, deg, b1, bufB, N);

        pool_kernel<<<GBATCH, 256, 0, stream>>>(bufB, batch, out, N);
    } else {
        char* p = (char*)d_ws;
        float* bufA = (float*)p;               p += (size_t)N * HDIM * 4;
        float* bufB = (float*)p;               p += (size_t)N * HDIM * 4;
        float* deg  = (float*)p;               p += (size_t)N * 4;
        int*   cnt  = (int*)p;

        const int NF = N * HDIM;
        const int scatGrid = (E * 32 + 255) / 256;
        init_kernel<<<(N + 255) / 256, 256, 0, stream>>>(deg, cnt, N);
        hist_kernel<<<(E + 255) / 256, 256, 0, stream>>>(ei, ew, deg, cnt, E);
        dinv_kernel<<<(N + 255) / 256, 256, 0, stream>>>(deg, N);

        gemm_kernel<0><<<gemmGrid, 256, 0, stream>>>(x, mapping, emb, nullptr, W0, bufA, N);
        self_init_kernel<<<(NF + 255) / 256, 256, 0, stream>>>(bufA, deg, b0, bufB, NF);
        scatter_kernel<<<scatGrid, 256, 0, stream>>>(ei, ew, deg, bufA, bufB, E);

        gemm_kernel<1><<<gemmGrid, 256, 0, stream>>>(nullptr, nullptr, nullptr, bufB, W1, bufA, N);
        self_init_kernel<<<(NF + 255) / 256, 256, 0, stream>>>(bufA, deg, b1, bufB, NF);
        scatter_kernel<<<scatGrid, 256, 0, stream>>>(ei, ew, deg, bufA, bufB, E);

        pool_kernel<<<GBATCH, 256, 0, stream>>>(bufB, batch, out, N);
    }
}